// Round 4
// baseline (200.869 us; speedup 1.0000x reference)
//
#include <hip/hip_runtime.h>

// Graph2Col: stable stream compaction of (m=128, V=2048, R=32) int32 mapping.
// Valid (!= -1) entries first in row-major order; tail filled with -1.
// Output layout in d_out (int32): nodes_indices [total*2] then column_indices [total*3].
//
// R11: occupancy/phase-concurrency experiment. R7..R10 established that global
//      store pattern dominates (dense int4 > reg-expand > scatter) and that the
//      LDS path is off the critical path (aligned-b128 copyout was neutral).
//      Remaining theory: 40KB LDS -> 4 blocks/CU (50% occ) + 3-barrier phasing
//      leaves the store pipe idle between per-block store bursts.
//      CHUNK 2048->1024: LDS = 20KB -> 8 blocks/CU (100% occ), 2x blocks for
//      finer phase interleave. Input load issued BEFORE the counts-scan so the
//      scan's independent work hides HBM latency. Head-alignment trick kept:
//      first (4-(excl&3))&3 records go direct to global, staged rest is 16B
//      aligned on LDS src and global dst -> pure ds_read_b128/dwordx4 copyout.

#define EMPTY_V (-1)

typedef int v2i __attribute__((ext_vector_type(2)));
typedef int v4i __attribute__((ext_vector_type(4)));

constexpr int TOTAL = 8388608;                 // 128*2048*32
constexpr int BLOCK = 256;
constexpr int CHUNK = 1024;                    // elements per block (1 int4/thread)
constexpr int NB = TOTAL / CHUNK;              // 8192 blocks
constexpr int NWAVE = BLOCK / 64;              // 4 waves

// ---------------------------------------------------------------- count pass
__global__ __launch_bounds__(BLOCK, 8) void k_count(const int* __restrict__ in,
                                                    int* __restrict__ counts) {
    const int b = blockIdx.x;
    const int tid = threadIdx.x;
    const int4 v = ((const int4*)(in + (size_t)b * CHUNK))[tid];
    int c = (v.x != EMPTY_V) + (v.y != EMPTY_V) + (v.z != EMPTY_V) + (v.w != EMPTY_V);
    for (int d = 32; d; d >>= 1) c += __shfl_down(c, d, 64);
    __shared__ int ws[NWAVE];
    const int lane = tid & 63, wid = tid >> 6;
    if (lane == 0) ws[wid] = c;
    __syncthreads();
    if (tid == 0) counts[b] = ws[0] + ws[1] + ws[2] + ws[3];
}

// ------- scatter: scan + head-aligned expanded staging + pure b128 copy-out
__global__ __launch_bounds__(BLOCK, 8) void k_scatter(const int* __restrict__ in,
                                                      const int* __restrict__ counts,
                                                      int* __restrict__ out_nodes,
                                                      int* __restrict__ out_cols) {
    const int b = blockIdx.x;
    const int tid = threadIdx.x;
    const int lane = tid & 63, wid = tid >> 6;
    const unsigned long long below = lane ? ((~0ull) >> (64 - lane)) : 0ull;

    __shared__ int s_nodes[2 * CHUNK];   // 8 KB (head 32 B doubles as scan scratch)
    __shared__ int s_cols[3 * CHUNK];    // 12 KB
    int* RED = s_nodes;                  // [NWAVE]  scan partials
    int* WSUM = s_nodes + NWAVE;         // [NWAVE]  per-wave valid totals

    // ---- issue the input load FIRST; scan work below hides its latency
    const int4 v = ((const int4*)(in + (size_t)b * CHUNK))[tid];

    // ---- per-wave partials of the redundant exclusive scan over counts[NB]
    {
        int pa = 0;
        const int idx0 = tid * 32;
#pragma unroll
        for (int q = 0; q < 8; ++q) {
            const int4 c4 = ((const int4*)counts)[8 * tid + q];
            const int cs[4] = {c4.x, c4.y, c4.z, c4.w};
#pragma unroll
            for (int j = 0; j < 4; ++j)
                if (idx0 + 4 * q + j < b) pa += cs[j];
        }
        for (int d = 32; d; d >>= 1) pa += __shfl_down(pa, d, 64);
        if (lane == 0) RED[wid] = pa;
    }

    // ---- ballots over the (now landed) input
    int pre;
    {
        const unsigned long long b0 = __ballot(v.x != EMPTY_V);
        const unsigned long long b1 = __ballot(v.y != EMPTY_V);
        const unsigned long long b2 = __ballot(v.z != EMPTY_V);
        const unsigned long long b3 = __ballot(v.w != EMPTY_V);
        pre = __popcll(b0 & below) + __popcll(b1 & below) +
              __popcll(b2 & below) + __popcll(b3 & below);
        if (lane == 0)
            WSUM[wid] = __popcll(b0) + __popcll(b1) + __popcll(b2) + __popcll(b3);
    }
    __syncthreads();   // barrier 1: RED/WSUM visible

    // ---- block-exclusive global prefix + per-thread local rank
    const int excl = RED[0] + RED[1] + RED[2] + RED[3];
    int woff = 0, nv = 0;
#pragma unroll
    for (int w = 0; w < NWAVE; ++w) {
        const int x = WSUM[w];
        nv += x;
        if (w < wid) woff += x;
    }
    const int myoff = woff + pre;        // local record rank within block
    __syncthreads();   // barrier 2: scratch consumed, staging may overwrite

    // ---- head-aligned staging: first `head` records go straight to global,
    //      the rest staged expanded at slot (rank - head).
    const int row = b >> 6;              // 65536 elems/output-row, 1024/block
    int head = (4 - (excl & 3)) & 3;
    if (head > nv) head = nv;
    {
        int lp = myoff;
        const int rem0 = ((b & 63) << 10) + (tid << 2);  // fi & 65535
        const int vals[4] = {v.x, v.y, v.z, v.w};
#pragma unroll
        for (int j = 0; j < 4; ++j) {
            if (vals[j] != EMPTY_V) {
                const int pp = rem0 + j;
                if (lp < head) {                       // <=3 records per block
                    const size_t g = (size_t)excl + lp;
                    out_nodes[2 * g] = row;  out_nodes[2 * g + 1] = vals[j];
                    out_cols[3 * g] = row;   out_cols[3 * g + 1] = pp >> 5;
                    out_cols[3 * g + 2] = pp & 31;
                } else {
                    const int sl = lp - head;
                    v2i nd = {row, vals[j]};
                    *(v2i*)&s_nodes[2 * sl] = nd;      // aligned ds_write_b64
                    s_cols[3 * sl] = row;
                    s_cols[3 * sl + 1] = pp >> 5;
                    s_cols[3 * sl + 2] = pp & 31;
                }
                ++lp;
            }
        }
    }
    __syncthreads();   // barrier 3: staging complete

    // ---- copy-out: both src and dst 16B-aligned -> pure b128 stream
    const int nrec = nv - head;                  // staged records (>= 0)
    const size_t g0 = (size_t)excl + head;       // g0 % 4 == 0 when nrec > 0
    {
        const int ndw = 2 * nrec, q = ndw >> 2;  // nodes: tail is 0 or 2 dwords
        v4i* dst = (v4i*)(out_nodes + 2 * g0);
        const v4i* src = (const v4i*)s_nodes;
        for (int k = tid; k < q; k += BLOCK) dst[k] = src[k];
        if ((ndw & 3) && tid < (ndw & 3))
            out_nodes[2 * g0 + 4 * q + tid] = s_nodes[4 * q + tid];
    }
    {
        const int ndw = 3 * nrec, q = ndw >> 2;  // cols: tail is 0..3 dwords
        v4i* dst = (v4i*)(out_cols + 3 * g0);
        const v4i* src = (const v4i*)s_cols;
        for (int k = tid; k < q; k += BLOCK) dst[k] = src[k];
        if (tid < (ndw & 3))
            out_cols[3 * g0 + 4 * q + tid] = s_cols[4 * q + tid];
    }

    // ---- tail: this block's invalid entries, counted from the end.
    {
        const int inv_pref = b * CHUNK - excl;            // invalids before this block
        const int start = TOTAL - inv_pref - (CHUNK - nv);
        const int end = TOTAL - inv_pref;
        for (int pos = start + tid; pos < end; pos += BLOCK) {
            out_nodes[2 * pos]     = EMPTY_V;
            out_nodes[2 * pos + 1] = EMPTY_V;
            out_cols[3 * pos]      = EMPTY_V;
            out_cols[3 * pos + 1]  = EMPTY_V;
            out_cols[3 * pos + 2]  = EMPTY_V;
        }
    }
}

extern "C" void kernel_launch(void* const* d_in, const int* in_sizes, int n_in,
                              void* d_out, int out_size, void* d_ws, size_t ws_size,
                              hipStream_t stream) {
    const int* in = (const int*)d_in[0];
    int* out = (int*)d_out;
    int* out_nodes = out;                    // [TOTAL, 2] int32
    int* out_cols = out + 2 * (size_t)TOTAL; // [TOTAL, 3] int32
    int* counts = (int*)d_ws;                // [NB] = 32 KB

    k_count<<<NB, BLOCK, 0, stream>>>(in, counts);
    k_scatter<<<NB, BLOCK, 0, stream>>>(in, counts, out_nodes, out_cols);
}

// Round 5
// 190.305 us; speedup vs baseline: 1.0555x; 1.0555x over previous
//
#include <hip/hip_runtime.h>

// Graph2Col: stable stream compaction of (m=128, V=2048, R=32) int32 mapping.
// Valid (!= -1) entries first in row-major order; tail filled with -1.
// Output layout in d_out (int32): nodes_indices [total*2] then column_indices [total*3].
//
// R12: clean occupancy test. CHUNK stays 2048 (R11's regression was the 4x
//      quadratic scan, not occupancy itself). LDS 40KB -> 16KB by staging only
//      (val, pp) pairs per record; copy-out reconstructs row/vertex/region in
//      registers but keeps the empirically-optimal store shape: every store
//      instruction is ONE int4 per thread at unit lane stride (dense full-line
//      wave stores). nodes: 1 ds_read_b128 (2 pairs) -> {row,v0,row,v1}.
//      cols: branch-free j%3 field select from 2 ds_read_b32 -> one int4.
//      16KB LDS + launch_bounds(256,8) => 8 blocks/CU (was 4).

#define EMPTY_V (-1)

typedef int v2i __attribute__((ext_vector_type(2)));
typedef int v4i __attribute__((ext_vector_type(4)));

constexpr int TOTAL = 8388608;                 // 128*2048*32
constexpr int BLOCK = 256;
constexpr int CHUNK = 2048;                    // elements per block
constexpr int NB = TOTAL / CHUNK;              // 4096 blocks
constexpr int SUBT = CHUNK / (BLOCK * 4);      // 2 sub-tiles of 1024 elements
constexpr int NWAVE = BLOCK / 64;              // 4 waves

// ---------------------------------------------------------------- count pass
__global__ __launch_bounds__(BLOCK) void k_count(const int* __restrict__ in,
                                                 int* __restrict__ counts) {
    const int b = blockIdx.x;
    const int tid = threadIdx.x;
    const int4* p = (const int4*)(in + (size_t)b * CHUNK);
    int c = 0;
#pragma unroll
    for (int s = 0; s < SUBT; ++s) {
        int4 v = p[s * BLOCK + tid];
        c += (v.x != EMPTY_V) + (v.y != EMPTY_V) + (v.z != EMPTY_V) + (v.w != EMPTY_V);
    }
    for (int d = 32; d; d >>= 1) c += __shfl_down(c, d, 64);
    __shared__ int ws[NWAVE];
    const int lane = tid & 63, wid = tid >> 6;
    if (lane == 0) ws[wid] = c;
    __syncthreads();
    if (tid == 0) counts[b] = ws[0] + ws[1] + ws[2] + ws[3];
}

// ---- scatter: scan + pair staging (16KB) + dense reconstructing copy-out
__global__ __launch_bounds__(BLOCK, 8) void k_scatter(const int* __restrict__ in,
                                                      const int* __restrict__ counts,
                                                      int* __restrict__ out_nodes,
                                                      int* __restrict__ out_cols) {
    const int b = blockIdx.x;
    const int tid = threadIdx.x;
    const int lane = tid & 63, wid = tid >> 6;
    const unsigned long long below = lane ? ((~0ull) >> (64 - lane)) : 0ull;

    __shared__ int s_pair[2 * CHUNK];    // 16 KB: compacted (val, pp) pairs
    int* RED = s_pair;                   // [NWAVE]      scan partials (overlay)
    int* WSUM = s_pair + NWAVE;          // [SUBT*NWAVE] per-subtile wave totals

    // ---- per-wave partials of the redundant exclusive scan over counts[NB]
    {
        int pa = 0;
        const int idx0 = tid * 16;
#pragma unroll
        for (int q = 0; q < 4; ++q) {
            const int4 c4 = ((const int4*)counts)[4 * tid + q];
            const int cs[4] = {c4.x, c4.y, c4.z, c4.w};
#pragma unroll
            for (int j = 0; j < 4; ++j)
                if (idx0 + 4 * q + j < b) pa += cs[j];
        }
        for (int d = 32; d; d >>= 1) pa += __shfl_down(pa, d, 64);
        if (lane == 0) RED[wid] = pa;
    }

    // ---- load chunk, ballots, publish per-wave totals
    int4 v[SUBT];
    int pre[SUBT];
    const int4* p = (const int4*)(in + (size_t)b * CHUNK);
#pragma unroll
    for (int s = 0; s < SUBT; ++s) {
        v[s] = p[s * BLOCK + tid];
        const unsigned long long b0 = __ballot(v[s].x != EMPTY_V);
        const unsigned long long b1 = __ballot(v[s].y != EMPTY_V);
        const unsigned long long b2 = __ballot(v[s].z != EMPTY_V);
        const unsigned long long b3 = __ballot(v[s].w != EMPTY_V);
        pre[s] = __popcll(b0 & below) + __popcll(b1 & below) +
                 __popcll(b2 & below) + __popcll(b3 & below);
        if (lane == 0)
            WSUM[s * NWAVE + wid] =
                __popcll(b0) + __popcll(b1) + __popcll(b2) + __popcll(b3);
    }
    __syncthreads();   // barrier 1: RED/WSUM visible

    // ---- block-exclusive global prefix + per-thread local ranks
    const int excl = RED[0] + RED[1] + RED[2] + RED[3];
    int myoff[SUBT];
    int acc = 0;
#pragma unroll
    for (int s = 0; s < SUBT; ++s) {
        int cs_ = 0, woff = 0;
#pragma unroll
        for (int w = 0; w < NWAVE; ++w) {
            const int x = WSUM[s * NWAVE + w];
            cs_ += x;
            if (w < wid) woff += x;
        }
        myoff[s] = acc + woff + pre[s];   // local record rank within block
        acc += cs_;
    }
    const int nv = acc;                   // blockValid
    __syncthreads();   // barrier 2: scratch consumed, staging may overwrite

    // ---- head-aligned pair staging: first `head` records direct to global
    const int row = b >> 5;              // 65536 elems per output row
    int head = (4 - (excl & 3)) & 3;
    if (head > nv) head = nv;
#pragma unroll
    for (int s = 0; s < SUBT; ++s) {
        int lp = myoff[s];
        const int rem0 = ((b & 31) << 11) + (s << 10) + (tid << 2);  // fi & 65535
        const int vals[4] = {v[s].x, v[s].y, v[s].z, v[s].w};
#pragma unroll
        for (int j = 0; j < 4; ++j) {
            if (vals[j] != EMPTY_V) {
                const int pp = rem0 + j;
                if (lp < head) {                       // <=3 records per block
                    const size_t g = (size_t)excl + lp;
                    out_nodes[2 * g] = row;  out_nodes[2 * g + 1] = vals[j];
                    out_cols[3 * g] = row;   out_cols[3 * g + 1] = pp >> 5;
                    out_cols[3 * g + 2] = pp & 31;
                } else {
                    const int sl = lp - head;
                    v2i t = {vals[j], pp};
                    *(v2i*)&s_pair[2 * sl] = t;        // aligned ds_write_b64
                }
                ++lp;
            }
        }
    }
    __syncthreads();   // barrier 3: staging complete

    const int nrec = nv - head;                  // staged records (>= 0)
    const size_t g0 = (size_t)excl + head;       // g0 % 4 == 0 when nrec > 0

    // ---- nodes copy-out: 2 records -> one dense int4 {row, v0, row, v1}
    {
        const int q2 = nrec >> 1;                // int4 count (2 recs each)
        v4i* dst = (v4i*)(out_nodes + 2 * g0);   // 16B-aligned (2*g0 % 4 == 0)
        const v4i* src = (const v4i*)s_pair;
        for (int m = tid; m < q2; m += BLOCK) {
            const v4i r = src[m];                // {v0, pp0, v1, pp1}
            v4i o = {row, r.x, row, r.z};
            dst[m] = o;
        }
        if ((nrec & 1) && tid == 0) {            // odd tail record
            const int l = nrec - 1;
            v2i o = {row, s_pair[2 * l]};
            *(v2i*)(out_nodes + 2 * (g0 + l)) = o;
        }
    }

    // ---- cols copy-out: one dense int4 per thread, branch-free j%3 select
    {
        const int ndw = 3 * nrec;
        const int qc = ndw >> 2;                 // int4 count
        v4i* dst = (v4i*)(out_cols + 3 * g0);    // 16B-aligned (3*g0 % 4 == 0)
        for (int j = tid; j < qc; j += BLOCK) {
            const int u = j / 3;                 // const-div (umulhi)
            const int m3 = j - 3 * u;
            const int recA = 4 * u + m3;         // in-range per alignment proof
            const int ppA = s_pair[2 * recA + 1];
            const int ppB = s_pair[2 * recA + 3];
            const int hA = ppA >> 5, lA = ppA & 31;
            const int hB = ppB >> 5, lB = ppB & 31;
            // m3==0: {row,hA,lA,row}  m3==1: {hA,lA,row,hB}  m3==2: {lA,row,hB,lB}
            const int x = (m3 == 0) ? row : ((m3 == 1) ? hA : lA);
            const int y = (m3 == 0) ? hA : ((m3 == 1) ? lA : row);
            const int z = (m3 == 0) ? lA : ((m3 == 1) ? row : hB);
            const int w = (m3 == 0) ? row : ((m3 == 1) ? hB : lB);
            v4i o = {x, y, z, w};
            dst[j] = o;
        }
        const int rem = ndw & 3;                 // 0..3 leftover dwords
        if (tid < rem) {
            const int P = 4 * qc + tid;
            const int r = P / 3, f = P - 3 * r;
            const int pp = s_pair[2 * r + 1];
            out_cols[3 * g0 + P] = (f == 0) ? row : ((f == 1) ? (pp >> 5) : (pp & 31));
        }
    }

    // ---- tail: this block's invalid entries, counted from the end.
    {
        const int inv_pref = b * CHUNK - excl;            // invalids before this block
        const int start = TOTAL - inv_pref - (CHUNK - nv);
        const int end = TOTAL - inv_pref;
        for (int pos = start + tid; pos < end; pos += BLOCK) {
            out_nodes[2 * pos]     = EMPTY_V;
            out_nodes[2 * pos + 1] = EMPTY_V;
            out_cols[3 * pos]      = EMPTY_V;
            out_cols[3 * pos + 1]  = EMPTY_V;
            out_cols[3 * pos + 2]  = EMPTY_V;
        }
    }
}

extern "C" void kernel_launch(void* const* d_in, const int* in_sizes, int n_in,
                              void* d_out, int out_size, void* d_ws, size_t ws_size,
                              hipStream_t stream) {
    const int* in = (const int*)d_in[0];
    int* out = (int*)d_out;
    int* out_nodes = out;                    // [TOTAL, 2] int32
    int* out_cols = out + 2 * (size_t)TOTAL; // [TOTAL, 3] int32
    int* counts = (int*)d_ws;                // [NB]

    k_count<<<NB, BLOCK, 0, stream>>>(in, counts);
    k_scatter<<<NB, BLOCK, 0, stream>>>(in, counts, out_nodes, out_cols);
}